// Round 7
// baseline (1347.382 us; speedup 1.0000x reference)
//
#include <hip/hip_runtime.h>

// SelectivePSI forward: bf16 MFMA GEMMs + chunked parallel scans.
// B=4, S=4096, D=1024, R=128. fp32 in/out, bf16 internals.
// Big GEMMs: 256x256 tile, BK=32, 8 waves (2x4), 64KB LDS dbuf, phase-split
// K-loop with one barrier per K-tile + chunk-XOR swizzle. Small GEMMs: 128² kernel.

#define D_ 1024
#define S_ 4096
#define MQ 4096              // tokens per quarter (B=1)
#define MF 16384             // full tokens
#define CHUNK 64
#define NCH (S_/CHUNK)       // 64 chunks per sequence

typedef float f32x4 __attribute__((ext_vector_type(4)));
typedef __bf16 bf16x8 __attribute__((ext_vector_type(8)));
typedef short s16x8 __attribute__((ext_vector_type(8)));

typedef __attribute__((address_space(1))) void gvoid;
typedef __attribute__((address_space(3))) void lvoid;

__device__ __forceinline__ void g2l16(const void* g, void* l) {
  __builtin_amdgcn_global_load_lds((gvoid*)g, (lvoid*)l, 16, 0, 0);
}

__device__ __forceinline__ float bflo(unsigned int w){ union{unsigned int i; float f;} c; c.i = w<<16; return c.f; }
__device__ __forceinline__ float bfhi(unsigned int w){ union{unsigned int i; float f;} c; c.i = w & 0xFFFF0000u; return c.f; }
__device__ __forceinline__ unsigned short f2bf(float f){
  union{float f; unsigned int i;} c; c.f=f;
  unsigned int u = c.i + 0x7FFFu + ((c.i>>16)&1u);
  return (unsigned short)(u>>16);
}
__device__ __forceinline__ unsigned int pack2(float lo, float hi){
  return (unsigned int)f2bf(lo) | ((unsigned int)f2bf(hi)<<16);
}

__device__ __forceinline__ float sig_(float x){ return 1.f/(1.f+__expf(-x)); }
__device__ __forceinline__ float gelu_(float x){ return 0.5f*x*(1.f+erff(x*0.70710678118654752440f)); }
__device__ __forceinline__ float softplus_(float x){ return (x>0.f) ? x + log1pf(__expf(-x)) : log1pf(__expf(x)); }

// ============ 256x256 GEMM, BK=32, 512 threads = 8 waves (2m x 4n) ============
// per-wave output 128x64 = acc[8][4]; LDS 64KB (2 bufs x (A 16KB + B 16KB)).
// SM 0: mega stage-1 (N=5120): slices n0>>10: 0 gate->sig,1 omega->lin,2 phi1->gelu,
//       3 mag->sig*5, 4 qoff->lin; out0 = cat1 [slice][MQ][1024].
// SM 1: p2 (K=1024): lin+bias -> out0.
// SM 2: out1 (lda=K=2048): gelu+bias -> out0.
// SM 3: out2: +bias +extra(x) residual -> fp32 outf.
template<int SM>
__global__ __launch_bounds__(512)
void gemm256(const unsigned short* __restrict__ A,
             const unsigned short* __restrict__ Bt,
             const float* __restrict__ bias,
             const float* __restrict__ extra,
             unsigned short* __restrict__ out0,
             float* __restrict__ outf)
{
  __shared__ unsigned short As[2][256*32];
  __shared__ unsigned short Bs[2][256*32];
  const int tid = threadIdx.x;
  const int m0 = blockIdx.x * 256;
  const int n0 = blockIdx.y * 256;
  const int lane = tid & 63;
  const int w  = tid >> 6;
  const int wm = w >> 2, wn = w & 3;
  const int fr = lane & 15, fg = lane >> 4;

  int lda, K;
  if constexpr (SM == 2) { lda = 2048; K = 2048; } else { lda = 1024; K = 1024; }
  const int ldb = K;

  // staging: thread covers rows rs, rs+128 at 16B chunk cs; source chunk swizzled
  const int rs = tid >> 2;
  const int cs = tid & 3;
  const int gch = (cs ^ (rs & 3)) * 8;            // swizzled source chunk (elements)
  const unsigned short* Asrc0 = A  + (size_t)(m0 + rs)       * lda + gch;
  const unsigned short* Asrc1 = A  + (size_t)(m0 + rs + 128) * lda + gch;
  const unsigned short* Bsrc0 = Bt + (size_t)(n0 + rs)       * ldb + gch;
  const unsigned short* Bsrc1 = Bt + (size_t)(n0 + rs + 128) * ldb + gch;

  // read side: logical chunk fg of row (..+fr) lives at slot fg ^ (fr&3)
  const int csw  = (fg ^ (fr & 3)) * 8;
  const int arow = wm*128 + fr;
  const int brow = wn*64  + fr;

  f32x4 acc[8][4];
#pragma unroll
  for (int i=0;i<8;i++)
#pragma unroll
    for (int j=0;j<4;j++)
#pragma unroll
      for (int q=0;q<4;q++) acc[i][j][q] = 0.f;

  auto STAGE = [&](int buf, int t) {
    const int k0 = t << 5;
    g2l16(Asrc0 + k0, &As[buf][(size_t)tid*8]);
    g2l16(Asrc1 + k0, &As[buf][(size_t)(tid+512)*8]);
    g2l16(Bsrc0 + k0, &Bs[buf][(size_t)tid*8]);
    g2l16(Bsrc1 + k0, &Bs[buf][(size_t)(tid+512)*8]);
  };
  auto COMPUTE = [&](int buf) {
    s16x8 bfr[4], af[4];
#pragma unroll
    for (int nf=0; nf<4; nf++) bfr[nf] = *(const s16x8*)&Bs[buf][(brow + nf*16)*32 + csw];
    // phase A: m-frags 0..3
#pragma unroll
    for (int mf=0; mf<4; mf++) af[mf] = *(const s16x8*)&As[buf][(arow + mf*16)*32 + csw];
    __builtin_amdgcn_s_setprio(1);
#pragma unroll
    for (int mf=0; mf<4; mf++)
#pragma unroll
      for (int nf=0; nf<4; nf++)
        acc[mf][nf] = __builtin_amdgcn_mfma_f32_16x16x32_bf16(
          __builtin_bit_cast(bf16x8, af[mf]), __builtin_bit_cast(bf16x8, bfr[nf]),
          acc[mf][nf], 0, 0, 0);
    __builtin_amdgcn_s_setprio(0);
    // phase B: m-frags 4..7
#pragma unroll
    for (int mf=0; mf<4; mf++) af[mf] = *(const s16x8*)&As[buf][(arow + (mf+4)*16)*32 + csw];
    __builtin_amdgcn_s_setprio(1);
#pragma unroll
    for (int mf=0; mf<4; mf++)
#pragma unroll
      for (int nf=0; nf<4; nf++)
        acc[mf+4][nf] = __builtin_amdgcn_mfma_f32_16x16x32_bf16(
          __builtin_bit_cast(bf16x8, af[mf]), __builtin_bit_cast(bf16x8, bfr[nf]),
          acc[mf+4][nf], 0, 0, 0);
    __builtin_amdgcn_s_setprio(0);
  };

  const int nt = K >> 5;
  STAGE(0, 0);
  asm volatile("s_waitcnt vmcnt(0)" ::: "memory");
  __builtin_amdgcn_s_barrier();
  __builtin_amdgcn_sched_barrier(0);
  for (int t = 0; t < nt - 1; ++t) {
    STAGE((t+1)&1, t+1);                     // prefetch next tile (other buffer)
    COMPUTE(t&1);
    __builtin_amdgcn_sched_barrier(0);       // keep this tile's ds_reads above
    asm volatile("s_waitcnt vmcnt(0)" ::: "memory");   // issued ~2 phases ago
    __builtin_amdgcn_s_barrier();            // all waves done reading buf[t&1]
    __builtin_amdgcn_sched_barrier(0);
  }
  COMPUTE((nt-1)&1);

  const int slice = n0 >> 10;
#pragma unroll
  for (int mf=0; mf<8; mf++) {
#pragma unroll
    for (int nf=0; nf<4; nf++) {
      const int gn = n0 + wn*64 + nf*16 + fr;
      const float bv = bias[gn];
#pragma unroll
      for (int q=0; q<4; q++) {
        const int gm = m0 + wm*128 + mf*16 + fg*4 + q;
        const float z = acc[mf][nf][q] + bv;
        if constexpr (SM == 0) {
          const float r = (slice==0) ? sig_(z)
                        : (slice==2) ? gelu_(z)
                        : (slice==3) ? sig_(z)*5.f : z;
          out0[(size_t)slice*MQ*1024 + (size_t)gm*1024 + (gn & 1023)] = f2bf(r);
        } else if constexpr (SM == 1) {
          out0[(size_t)gm*1024 + gn] = f2bf(z);
        } else if constexpr (SM == 2) {
          out0[(size_t)gm*1024 + gn] = f2bf(gelu_(z));
        } else {
          const size_t idx = (size_t)gm*1024 + gn;
          outf[idx] = z + extra[idx];
        }
      }
    }
  }
}

// ============ 128x128 GEMM (small shapes: dt_down, dt_up) ============
// MODE 0: A0/B0 (K=1024), slice-5 path when n0>=5120 -> out1 = t1[MQ][128] (no act).
// MODE 1: n0>=1024 -> A1=t1(lda=128,K=128), B1=wt_du -> out1 softplus (dt).
template<int MODE>
__global__ __launch_bounds__(256)
void gemmF(const unsigned short* __restrict__ A0,
           const unsigned short* __restrict__ A1,
           const unsigned short* __restrict__ B0,
           const unsigned short* __restrict__ B1,
           const float* __restrict__ bias0,
           const float* __restrict__ bias1,
           int n0ofs,
           unsigned short* __restrict__ out0,
           unsigned short* __restrict__ out1)
{
  __shared__ unsigned short As[2][128*32];
  __shared__ unsigned short Bs[2][128*32];
  const int tid = threadIdx.x;
  const int m0 = blockIdx.x * 128;
  const int n0 = blockIdx.y * 128 + n0ofs;
  const int lane = tid & 63;
  const int wv = tid >> 6;
  const int wr = wv >> 1, wc = wv & 1;
  const int fr = lane & 15, fg = lane >> 4;

  const int r0 = tid >> 2;
  const int c4 = tid & 3;
  const int k8s = (c4 ^ ((r0 >> 1) & 3)) * 8;
  const int csw = (fg ^ ((fr >> 1) & 3)) * 8;

  const unsigned short* Ap; const unsigned short* Bp;
  int lda, ldb, K, brow0;
  if constexpr (MODE == 0)      { Ap=A0; lda=1024; K=1024; Bp=B0; ldb=1024; brow0=n0; }
  else {
    Ap=A1; lda=128; K=128; Bp=B1; ldb=128; brow0=n0-1024;
  }

  const unsigned short* ArowA = Ap + (size_t)(m0+r0)*lda + k8s;
  const unsigned short* ArowB = Ap + (size_t)(m0+r0+64)*lda + k8s;
  const unsigned short* BrowA = Bp + (size_t)(brow0+r0)*ldb + k8s;
  const unsigned short* BrowB = Bp + (size_t)(brow0+r0+64)*ldb + k8s;

  f32x4 acc[4][4];
#pragma unroll
  for (int i=0;i<4;i++)
#pragma unroll
    for (int j=0;j<4;j++)
#pragma unroll
      for (int q=0;q<4;q++) acc[i][j][q] = 0.f;

  auto STAGE = [&](int buf, int t) {
    const int k0 = t << 5;
    g2l16(ArowA + k0, &As[buf][(size_t)tid*8]);
    g2l16(ArowB + k0, &As[buf][(size_t)(tid+256)*8]);
    g2l16(BrowA + k0, &Bs[buf][(size_t)tid*8]);
    g2l16(BrowB + k0, &Bs[buf][(size_t)(tid+256)*8]);
  };
  auto COMPUTE = [&](int buf) {
    s16x8 af[4], bfr[4];
#pragma unroll
    for (int mf=0; mf<4; mf++) af[mf]  = *(const s16x8*)&As[buf][(wr*64 + mf*16 + fr)*32 + csw];
#pragma unroll
    for (int nf=0; nf<4; nf++) bfr[nf] = *(const s16x8*)&Bs[buf][(wc*64 + nf*16 + fr)*32 + csw];
    __builtin_amdgcn_s_setprio(1);
#pragma unroll
    for (int mf=0; mf<4; mf++)
#pragma unroll
      for (int nf=0; nf<4; nf++)
        acc[mf][nf] = __builtin_amdgcn_mfma_f32_16x16x32_bf16(
          __builtin_bit_cast(bf16x8, af[mf]), __builtin_bit_cast(bf16x8, bfr[nf]),
          acc[mf][nf], 0, 0, 0);
    __builtin_amdgcn_s_setprio(0);
  };

  const int nt = K >> 5;
  STAGE(0, 0);
  asm volatile("s_waitcnt vmcnt(0)" ::: "memory");
  __builtin_amdgcn_s_barrier();
  __builtin_amdgcn_sched_barrier(0);
  for (int t = 0; t < nt - 1; ++t) {
    STAGE((t+1)&1, t+1);
    COMPUTE(t&1);
    __builtin_amdgcn_sched_barrier(0);
    asm volatile("s_waitcnt vmcnt(0)" ::: "memory");
    __builtin_amdgcn_s_barrier();
    __builtin_amdgcn_sched_barrier(0);
  }
  COMPUTE((nt-1)&1);

#pragma unroll
  for (int mf=0; mf<4; mf++) {
#pragma unroll
    for (int nf=0; nf<4; nf++) {
      const int gn = n0 + wc*64 + nf*16 + fr;
      float bv;
      if constexpr (MODE == 0) bv = bias0[gn];
      else bv = bias1[gn-1024];
#pragma unroll
      for (int q=0; q<4; q++) {
        const int gm = m0 + wr*64 + mf*16 + fg*4 + q;
        const float z = acc[mf][nf][q] + bv;
        if constexpr (MODE == 0) {
          out1[(size_t)gm*128 + (gn-5120)] = f2bf(z);          // dt_down -> t1
        } else {
          out1[(size_t)gm*1024 + (gn-1024)] = f2bf(softplus_(z)); // dt_up -> zdt
        }
      }
    }
  }
}

// ---------------- prep kernels ----------------
__global__ __launch_bounds__(256)
void cvtx_k(const float* __restrict__ x, unsigned int* __restrict__ hb)
{
  const size_t i = (size_t)blockIdx.x*256 + threadIdx.x;
  const float4 v = *(const float4*)(x + i*4);
  hb[i*2]   = pack2(v.x, v.y);
  hb[i*2+1] = pack2(v.z, v.w);
}

__global__ __launch_bounds__(256)
void tconv_k(const float* __restrict__ W, unsigned short* __restrict__ Wt, int K, int N)
{
  __shared__ float tile[32][33];
  const int kb = blockIdx.x*32, nb = blockIdx.y*32;
  const int tx = threadIdx.x & 31, ty = threadIdx.x >> 5;
#pragma unroll
  for (int i=0;i<32;i+=8) tile[ty+i][tx] = W[(size_t)(kb+ty+i)*N + (nb+tx)];
  __syncthreads();
#pragma unroll
  for (int i=0;i<32;i+=8) Wt[(size_t)(nb+ty+i)*K + (kb+tx)] = f2bf(tile[tx][ty+i]);
}

struct P7 { const float* s[7]; unsigned short* d[7]; };
__global__ __launch_bounds__(256)
void tconv7_k(P7 p)
{
  __shared__ float tile[32][33];
  const float* W = p.s[blockIdx.z];
  unsigned short* Wt = p.d[blockIdx.z];
  const int kb = blockIdx.x*32, nb = blockIdx.y*32;
  const int tx = threadIdx.x & 31, ty = threadIdx.x >> 5;
#pragma unroll
  for (int i=0;i<32;i+=8) tile[ty+i][tx] = W[(size_t)(kb+ty+i)*1024 + (nb+tx)];
  __syncthreads();
#pragma unroll
  for (int i=0;i<32;i+=8) Wt[(size_t)(nb+ty+i)*1024 + (kb+tx)] = f2bf(tile[tx][ty+i]);
}

__global__ __launch_bounds__(256)
void biascat_k(const float* bg, const float* bo, const float* ob, const float* bp1,
               const float* bm, const float* bq, float* bc)
{
  const int i = blockIdx.x*256 + threadIdx.x;
  if (i >= 5248) return;
  const int s = i >> 10, d = i & 1023;
  float v;
  if (s==0) v = bg[d];
  else if (s==1) v = bo[d] + ob[d];
  else if (s==2) v = bp1[d];
  else if (s==3) v = bm[d];
  else if (s==4) v = bq[d];
  else v = 0.f;
  bc[i] = v;
}

// ---------------- scans (quarter = 1 batch, 64 chunks of 64 steps) ----------------
__global__ __launch_bounds__(256)
void scan1_k(unsigned int* __restrict__ zgate, unsigned int* __restrict__ zmag,
             unsigned int* __restrict__ zomega, const unsigned int* __restrict__ zdt,
             const unsigned int* __restrict__ hb,
             float* __restrict__ sumPhi, float* __restrict__ sumGm)
{
  const int flat = blockIdx.x*256 + threadIdx.x;
  const int dh = flat & 511;
  const int bc = flat >> 9;
  size_t i = (size_t)bc*CHUNK*(D_/2) + dh;
  float sp0=0,sp1=0,sg0=0,sg1=0;
  for (int s=0;s<CHUNK;s++,i+=D_/2) {
    const unsigned ga=zgate[i], mg=zmag[i], om=zomega[i], dt=zdt[i], hh=hb[i];
    const float ga0=bflo(ga), ga1=bfhi(ga), mg0=bflo(mg), mg1=bfhi(mg);
    const float od0 = bflo(om)*bflo(dt)*0.01f, od1 = bfhi(om)*bfhi(dt)*0.01f;
    const unsigned odp = pack2(od0, od1);
    zomega[i] = odp;
    sp0 += bflo(odp); sp1 += bfhi(odp);
    const float g0 = ga0*mg0, g1 = ga1*mg1;
    const unsigned gmp = pack2(g0, g1);
    zmag[i] = gmp;
    sg0 += bflo(gmp); sg1 += bfhi(gmp);
    zgate[i] = pack2(g0*bflo(hh), g1*bfhi(hh));
  }
  const int sidx = bc*D_ + dh*2;
  sumPhi[sidx]=sp0; sumPhi[sidx+1]=sp1;
  sumGm[sidx]=sg0;  sumGm[sidx+1]=sg1;
}

__global__ __launch_bounds__(256)
void scan2_k(float* __restrict__ a, float* __restrict__ b)
{
  const int chain = (blockIdx.x*256 + threadIdx.x) >> 6;
  const int lane  = threadIdx.x & 63;
  const size_t i = (size_t)lane*D_ + chain;
  const float v = a[i], w = b[i];
  float vi = v, wi = w;
#pragma unroll
  for (int off=1; off<64; off<<=1) {
    const float t = __shfl_up(vi, off, 64);
    const float u = __shfl_up(wi, off, 64);
    if (lane >= off) { vi += t; wi += u; }
  }
  a[i] = vi - v;
  b[i] = wi - w;
}

__global__ __launch_bounds__(256)
void scan3_k(const unsigned int* __restrict__ omdt, const unsigned int* __restrict__ content,
             const unsigned int* __restrict__ phinit, const float* __restrict__ phiOff,
             float* __restrict__ sumRe, float* __restrict__ sumIm)
{
  const int flat = blockIdx.x*256 + threadIdx.x;
  const int dh = flat & 511;
  const int bc = flat >> 9;
  size_t i = (size_t)bc*CHUNK*(D_/2) + dh;
  const int sidx = bc*D_ + dh*2;
  float p0 = phiOff[sidx], p1 = phiOff[sidx+1];
  float re0=0,re1=0,im0=0,im1=0;
  for (int s=0;s<CHUNK;s++,i+=D_/2) {
    const unsigned od = omdt[i], ct = content[i], pi = phinit[i];
    p0 += bflo(od); p1 += bfhi(od);
    const float phi0 = bflo(pi)+p0, phi1 = bfhi(pi)+p1;
    float s0,c0,s1,c1;
    __sincosf(phi0,&s0,&c0);
    __sincosf(phi1,&s1,&c1);
    const float ct0=bflo(ct), ct1=bfhi(ct);
    re0 += ct0*c0; im0 += ct0*s0;
    re1 += ct1*c1; im1 += ct1*s1;
  }
  sumRe[sidx]=re0; sumRe[sidx+1]=re1;
  sumIm[sidx]=im0; sumIm[sidx+1]=im1;
}

__global__ __launch_bounds__(256)
void scan5_k(const unsigned int* __restrict__ omdt, const unsigned int* __restrict__ content,
             const unsigned int* __restrict__ phinit, const unsigned int* __restrict__ gm,
             const unsigned int* __restrict__ qoff,
             const float* __restrict__ phiOff, const float* __restrict__ gmOff,
             const float* __restrict__ reOff, const float* __restrict__ imOff,
             unsigned int* __restrict__ ctx)
{
  const int flat = blockIdx.x*256 + threadIdx.x;
  const int dh = flat & 511;
  const int bc = flat >> 9;
  size_t i = (size_t)bc*CHUNK*(D_/2) + dh;
  const int sidx = bc*D_ + dh*2;
  float p0 = phiOff[sidx], p1 = phiOff[sidx+1];
  float ag0 = gmOff[sidx], ag1 = gmOff[sidx+1];
  float re0 = reOff[sidx], re1 = reOff[sidx+1];
  float im0 = imOff[sidx], im1 = imOff[sidx+1];
  const int mtok0 = bc*CHUNK;
  for (int s=0;s<CHUNK;s++,i+=D_/2) {
    const unsigned od = omdt[i], ct = content[i], pi = phinit[i], gq = gm[i], qo = qoff[i];
    p0 += bflo(od); p1 += bfhi(od);
    const float phi0 = bflo(pi)+p0, phi1 = bfhi(pi)+p1;
    float sn0,cs0,sn1,cs1;
    __sincosf(phi0,&sn0,&cs0);
    __sincosf(phi1,&sn1,&cs1);
    const float ct0=bflo(ct), ct1=bfhi(ct);
    re0 += ct0*cs0; im0 += ct0*sn0;
    re1 += ct1*cs1; im1 += ct1*sn1;
    ag0 += bflo(gq); ag1 += bfhi(gq);
    const float inv0 = rsqrtf(ag0 + 1e-8f), inv1 = rsqrtf(ag1 + 1e-8f);
    const float mr0 = re0*inv0, mi0 = im0*inv0;
    const float mr1 = re1*inv1, mi1 = im1*inv1;
    const float pq0 = phi0 + bflo(qo), pq1 = phi1 + bfhi(qo);
    float sq0,cq0,sq1,cq1;
    __sincosf(pq0,&sq0,&cq0);
    __sincosf(pq1,&sq1,&cq1);
    const size_t cb = (size_t)(mtok0+s)*D_ + dh;
    ctx[cb]        = pack2(mr0*cq0 + mi0*sq0, mr1*cq1 + mi1*sq1);
    ctx[cb + D_/2] = pack2(mi0*cq0 - mr0*sq0, mi1*cq1 - mr1*sq1);
  }
}

__global__ __launch_bounds__(256)
void ln_k(unsigned int* __restrict__ ctx, const float* __restrict__ gam, const float* __restrict__ bet)
{
  const int m = blockIdx.x, tid = threadIdx.x;
  const size_t base = (size_t)m*1024 + tid*4;
  const uint4 t = *(const uint4*)(ctx + base);
  float v[8] = { bflo(t.x), bfhi(t.x), bflo(t.y), bfhi(t.y),
                 bflo(t.z), bfhi(t.z), bflo(t.w), bfhi(t.w) };
  float s=0.f, ss=0.f;
#pragma unroll
  for (int j=0;j<8;j++){ s+=v[j]; ss+=v[j]*v[j]; }
  for (int o=32;o;o>>=1){ s += __shfl_xor(s,o); ss += __shfl_xor(ss,o); }
  __shared__ float red[8];
  const int wv = tid>>6, lane = tid&63;
  if (lane==0){ red[wv]=s; red[4+wv]=ss; }
  __syncthreads();
  s  = red[0]+red[1]+red[2]+red[3];
  ss = red[4]+red[5]+red[6]+red[7];
  const float mu = s*(1.f/2048.f);
  const float rstd = rsqrtf(ss*(1.f/2048.f) - mu*mu + 1e-5f);
  const int col = tid*8;
  float o[8];
#pragma unroll
  for (int j=0;j<8;j++) o[j] = (v[j]-mu)*rstd*gam[col+j] + bet[col+j];
  uint4 w;
  w.x = pack2(o[0],o[1]); w.y = pack2(o[2],o[3]);
  w.z = pack2(o[4],o[5]); w.w = pack2(o[6],o[7]);
  *(uint4*)(ctx + base) = w;
}

extern "C" void kernel_launch(void* const* d_in, const int* in_sizes, int n_in,
                              void* d_out, int out_size, void* d_ws, size_t ws_size,
                              hipStream_t stream)
{
  const float* x     = (const float*)d_in[0];
  const float* Wdd   = (const float*)d_in[1];
  const float* Wdu   = (const float*)d_in[2];
  const float* bdu   = (const float*)d_in[3];
  const float* Wg    = (const float*)d_in[4];
  const float* bg    = (const float*)d_in[5];
  const float* Wp1   = (const float*)d_in[6];
  const float* bp1   = (const float*)d_in[7];
  const float* Wp2   = (const float*)d_in[8];
  const float* bp2   = (const float*)d_in[9];
  const float* obase = (const float*)d_in[10];
  const float* Wo    = (const float*)d_in[11];
  const float* bo    = (const float*)d_in[12];
  const float* Wm    = (const float*)d_in[13];
  const float* bm    = (const float*)d_in[14];
  const float* Wq    = (const float*)d_in[15];
  const float* bq    = (const float*)d_in[16];
  const float* lng   = (const float*)d_in[17];
  const float* lnb   = (const float*)d_in[18];
  const float* Wo1   = (const float*)d_in[19];
  const float* bo1   = (const float*)d_in[20];
  const float* Wo2   = (const float*)d_in[21];
  const float* bo2   = (const float*)d_in[22];

  char* basep = (char*)d_ws;
  size_t off = 0;
  auto alloc = [&](size_t n) { char* q = basep + off; off = (off + n + 255) & ~(size_t)255; return q; };

  unsigned short* ctxF = (unsigned short*)alloc((size_t)MF*2048*2);        // 67.1 MB
  char* qbase = alloc((size_t)5*MQ*1024*2 + (size_t)2*MQ*1024*2
                      + (size_t)MQ*1024*2 + (size_t)MQ*128*2);             // 68.2 MB
  unsigned short* cat1 = (unsigned short*)qbase;
  unsigned short* cat2 = cat1 + (size_t)5*MQ*1024;
  unsigned short* hb   = cat2 + (size_t)2*MQ*1024;
  unsigned short* t1   = hb   + (size_t)MQ*1024;
  unsigned short* a3   = (unsigned short*)qbase;                            // tail only
  unsigned short* wt_cat = (unsigned short*)alloc((size_t)5248*1024*2);
  unsigned short* wt_p2  = (unsigned short*)alloc(1024*1024*2);
  unsigned short* wt_du  = (unsigned short*)alloc(1024*128*2);
  unsigned short* wt_o1  = (unsigned short*)alloc((size_t)1024*2048*2);
  unsigned short* wt_o2  = (unsigned short*)alloc(1024*1024*2);
  float* bias_cat = (float*)alloc(5248*4);
  float* sumPhi = (float*)alloc((size_t)NCH*D_*4);
  float* sumGm  = (float*)alloc((size_t)NCH*D_*4);
  float* sumRe  = (float*)alloc((size_t)NCH*D_*4);
  float* sumIm  = (float*)alloc((size_t)NCH*D_*4);

  const dim3 blk(256);
  const dim3 blk512(512);

  P7 p7;
  p7.s[0]=Wg;  p7.d[0]=wt_cat + (size_t)0*1024*1024;
  p7.s[1]=Wo;  p7.d[1]=wt_cat + (size_t)1*1024*1024;
  p7.s[2]=Wp1; p7.d[2]=wt_cat + (size_t)2*1024*1024;
  p7.s[3]=Wm;  p7.d[3]=wt_cat + (size_t)3*1024*1024;
  p7.s[4]=Wq;  p7.d[4]=wt_cat + (size_t)4*1024*1024;
  p7.s[5]=Wp2; p7.d[5]=wt_p2;
  p7.s[6]=Wo2; p7.d[6]=wt_o2;
  tconv7_k<<<dim3(32,32,7), blk, 0, stream>>>(p7);
  tconv_k<<<dim3(32,4),  blk, 0, stream>>>(Wdd, wt_cat + (size_t)5120*1024, 1024,128);
  tconv_k<<<dim3(4,32),  blk, 0, stream>>>(Wdu, wt_du, 128,1024);
  tconv_k<<<dim3(64,32), blk, 0, stream>>>(Wo1, wt_o1, 2048,1024);
  biascat_k<<<21, blk, 0, stream>>>(bg, bo, obase, bp1, bm, bq, bias_cat);

  unsigned short* zgate  = cat1;
  unsigned short* zomega = cat1 + (size_t)1*MQ*1024;
  unsigned short* zphi1  = cat1 + (size_t)2*MQ*1024;
  unsigned short* zmag   = cat1 + (size_t)3*MQ*1024;
  unsigned short* zqoff  = cat1 + (size_t)4*MQ*1024;
  unsigned short* zpin   = cat2;
  unsigned short* zdt    = cat2 + (size_t)1*MQ*1024;

  for (int q = 0; q < 4; q++) {
    const float* xq = x + (size_t)q*MQ*D_;

    cvtx_k<<<MQ*D_/1024, blk, 0, stream>>>(xq, (unsigned int*)hb);

    // stage-1 mega (N=5120, 256² kernel) + dt_down (128² kernel)
    gemm256<0><<<dim3(MQ/256, 20), blk512, 0, stream>>>(hb, wt_cat, bias_cat,
                                                        nullptr, cat1, nullptr);
    gemmF<0><<<dim3(MQ/128, 1), blk, 0, stream>>>(hb, nullptr, wt_cat, nullptr,
                                                  bias_cat, nullptr, 5120, nullptr, t1);
    // p2 (256²) + dt_up (128²)
    gemm256<1><<<dim3(MQ/256, 4), blk512, 0, stream>>>(zphi1, wt_p2, bp2,
                                                       nullptr, zpin, nullptr);
    gemmF<1><<<dim3(MQ/128, 8), blk, 0, stream>>>(nullptr, t1, nullptr, wt_du,
                                                  nullptr, bdu, 1024, nullptr, zdt);
    // scans
    scan1_k<<<128, blk, 0, stream>>>((unsigned int*)zgate,(unsigned int*)zmag,(unsigned int*)zomega,
                                     (const unsigned int*)zdt,(const unsigned int*)hb, sumPhi, sumGm);
    scan2_k<<<256, blk, 0, stream>>>(sumPhi, sumGm);
    scan3_k<<<128, blk, 0, stream>>>((const unsigned int*)zomega,(const unsigned int*)zgate,
                                     (const unsigned int*)zpin, sumPhi, sumRe, sumIm);
    scan2_k<<<256, blk, 0, stream>>>(sumRe, sumIm);
    scan5_k<<<128, blk, 0, stream>>>((const unsigned int*)zomega,(const unsigned int*)zgate,
                                     (const unsigned int*)zpin,(const unsigned int*)zmag,
                                     (const unsigned int*)zqoff,
                                     sumPhi, sumGm, sumRe, sumIm,
                                     (unsigned int*)ctxF + (size_t)q*MQ*1024);
  }

  // full-batch tail: LN + out MLP + residual (256² kernel, grid = 256 blocks)
  ln_k<<<MF, blk, 0, stream>>>((unsigned int*)ctxF, lng, lnb);
  gemm256<2><<<dim3(MF/256, 4), blk512, 0, stream>>>(ctxF, wt_o1, bo1,
                                                     nullptr, a3, nullptr);
  gemm256<3><<<dim3(MF/256, 4), blk512, 0, stream>>>(a3, wt_o2, bo2,
                                                     x, nullptr, (float*)d_out);
}

// Round 8
// 830.794 us; speedup vs baseline: 1.6218x; 1.6218x over previous
//
#include <hip/hip_runtime.h>

// SelectivePSI forward: bf16 MFMA GEMMs + chunked parallel scans.
// B=4, S=4096, D=1024, R=128. fp32 in/out, bf16 internals.
// Half-split (B=2 per pass). dt low-rank folded into mega-GEMM via Wcomb=Wdd@Wdu.
// GEMM inner loop = round-5 structure (2-buf LDS, counted vmcnt(4), raw barriers).

#define D_ 1024
#define S_ 4096
#define MH 8192              // tokens per half (B=2)
#define CHUNK 64

typedef float f32x4 __attribute__((ext_vector_type(4)));
typedef __bf16 bf16x8 __attribute__((ext_vector_type(8)));
typedef short s16x8 __attribute__((ext_vector_type(8)));

typedef __attribute__((address_space(1))) void gvoid;
typedef __attribute__((address_space(3))) void lvoid;

__device__ __forceinline__ void g2l16(const void* g, void* l) {
  __builtin_amdgcn_global_load_lds((gvoid*)g, (lvoid*)l, 16, 0, 0);
}

__device__ __forceinline__ float bflo(unsigned int w){ union{unsigned int i; float f;} c; c.i = w<<16; return c.f; }
__device__ __forceinline__ float bfhi(unsigned int w){ union{unsigned int i; float f;} c; c.i = w & 0xFFFF0000u; return c.f; }
__device__ __forceinline__ unsigned short f2bf(float f){
  union{float f; unsigned int i;} c; c.f=f;
  unsigned int u = c.i + 0x7FFFu + ((c.i>>16)&1u);
  return (unsigned short)(u>>16);
}
__device__ __forceinline__ unsigned int pack2(float lo, float hi){
  return (unsigned int)f2bf(lo) | ((unsigned int)f2bf(hi)<<16);
}

__device__ __forceinline__ float sig_(float x){ return 1.f/(1.f+__expf(-x)); }
__device__ __forceinline__ float gelu_(float x){ return 0.5f*x*(1.f+erff(x*0.70710678118654752440f)); }
__device__ __forceinline__ float softplus_(float x){ return (x>0.f) ? x + log1pf(__expf(-x)) : log1pf(__expf(x)); }

// ---------------- GEMM: C[M,N] = A[M,KK] @ Bt[N,KK]^T, 128x128 tile, BK=32 ----------------
// EPI 0: mega (N=6144): slice n0>>10: 0 omega->lin(+base in bias), 1 mag->sig*5,
//        2 qoff->lin, 3 gate->sig, 4 dt->softplus, 5 phi1->gelu; out0[slice][MH][1024].
// EPI 1: lin+bias -> out0            (p2 -> zpin)
// EPI 2: gelu+bias -> out0           (out1 -> a3)
// EPI 3: lin+bias+extra -> fp32 outf (out2 + residual)
// EPI 4: lin no-bias -> out0         (Wcomb prep, M=N=1024, KK=128)
template<int EPI, int KK>
__global__ __launch_bounds__(256)
void gemmH(const unsigned short* __restrict__ A,
           const unsigned short* __restrict__ Bt,
           const float* __restrict__ bias,
           const float* __restrict__ extra,
           unsigned short* __restrict__ out0,
           float* __restrict__ outf)
{
  __shared__ unsigned short As[2][128*32];
  __shared__ unsigned short Bs[2][128*32];
  const int tid = threadIdx.x;
  const int m0 = blockIdx.x * 128;
  const int n0 = blockIdx.y * 128;
  const int lane = tid & 63;
  const int wv = tid >> 6;
  const int wr = wv >> 1, wc = wv & 1;
  const int fr = lane & 15, fg = lane >> 4;

  const int r0 = tid >> 2;
  const int k8 = (tid & 3) * 8;

  const unsigned short* ArowA = A  + (size_t)(m0+r0)*KK + k8;
  const unsigned short* ArowB = A  + (size_t)(m0+r0+64)*KK + k8;
  const unsigned short* BrowA = Bt + (size_t)(n0+r0)*KK + k8;
  const unsigned short* BrowB = Bt + (size_t)(n0+r0+64)*KK + k8;

  f32x4 acc[4][4];
#pragma unroll
  for (int i=0;i<4;i++)
#pragma unroll
    for (int j=0;j<4;j++)
#pragma unroll
      for (int q=0;q<4;q++) acc[i][j][q] = 0.f;

  auto STAGE = [&](int buf, int t) {
    const int k0 = t << 5;
    g2l16(ArowA + k0, &As[buf][(size_t)tid*8]);
    g2l16(ArowB + k0, &As[buf][(size_t)(tid+256)*8]);
    g2l16(BrowA + k0, &Bs[buf][(size_t)tid*8]);
    g2l16(BrowB + k0, &Bs[buf][(size_t)(tid+256)*8]);
  };
  auto COMPUTE = [&](int buf) {
    s16x8 af[4], bfr[4];
#pragma unroll
    for (int mf=0; mf<4; mf++) af[mf]  = *(const s16x8*)&As[buf][(wr*64 + mf*16 + fr)*32 + fg*8];
#pragma unroll
    for (int nf=0; nf<4; nf++) bfr[nf] = *(const s16x8*)&Bs[buf][(wc*64 + nf*16 + fr)*32 + fg*8];
#pragma unroll
    for (int mf=0; mf<4; mf++)
#pragma unroll
      for (int nf=0; nf<4; nf++)
        acc[mf][nf] = __builtin_amdgcn_mfma_f32_16x16x32_bf16(
          __builtin_bit_cast(bf16x8, af[mf]), __builtin_bit_cast(bf16x8, bfr[nf]),
          acc[mf][nf], 0, 0, 0);
  };

  const int nt = KK >> 5;            // >= 4 always
  STAGE(0, 0);
  STAGE(1, 1);
  int cur = 0;
  for (int t = 0; t < nt - 1; ++t) {
    asm volatile("s_waitcnt vmcnt(4)" ::: "memory");   // retire current tile only
    __builtin_amdgcn_s_barrier();
    __builtin_amdgcn_sched_barrier(0);
    COMPUTE(cur);
    __builtin_amdgcn_s_barrier();
    __builtin_amdgcn_sched_barrier(0);
    if (t + 2 < nt) STAGE(cur, t + 2);
    cur ^= 1;
  }
  asm volatile("s_waitcnt vmcnt(0)" ::: "memory");
  __builtin_amdgcn_s_barrier();
  __builtin_amdgcn_sched_barrier(0);
  COMPUTE(cur);

  const int slice = n0 >> 10;
#pragma unroll
  for (int mf=0; mf<4; mf++) {
#pragma unroll
    for (int nf=0; nf<4; nf++) {
      const int gn = n0 + wc*64 + nf*16 + fr;
      float bv = 0.f;
      if constexpr (EPI != 4) bv = bias[gn];
#pragma unroll
      for (int q=0; q<4; q++) {
        const int gm = m0 + wr*64 + mf*16 + fg*4 + q;
        const float z = acc[mf][nf][q] + bv;
        if constexpr (EPI == 0) {
          const float r = (slice==1) ? sig_(z)*5.f
                        : (slice==3) ? sig_(z)
                        : (slice==4) ? softplus_(z)
                        : (slice==5) ? gelu_(z) : z;   // 0 omega, 2 qoff: linear
          out0[(size_t)slice*((size_t)MH*1024) + (size_t)gm*1024 + (gn & 1023)] = f2bf(r);
        } else if constexpr (EPI == 1) {
          out0[(size_t)gm*1024 + gn] = f2bf(z);
        } else if constexpr (EPI == 2) {
          out0[(size_t)gm*1024 + gn] = f2bf(gelu_(z));
        } else if constexpr (EPI == 3) {
          const size_t idx = (size_t)gm*1024 + gn;
          outf[idx] = z + extra[idx];
        } else {
          out0[(size_t)gm*1024 + gn] = f2bf(z);        // Wcomb
        }
      }
    }
  }
}

// ---------------- prep kernels ----------------
__global__ __launch_bounds__(256)
void cvtx_k(const float* __restrict__ x, unsigned int* __restrict__ hb)
{
  const size_t i = (size_t)blockIdx.x*256 + threadIdx.x;
  const float4 v = *(const float4*)(x + i*4);
  hb[i*2]   = pack2(v.x, v.y);
  hb[i*2+1] = pack2(v.z, v.w);
}

__global__ __launch_bounds__(256)
void tconv_k(const float* __restrict__ W, unsigned short* __restrict__ Wt, int K, int N)
{
  __shared__ float tile[32][33];
  const int kb = blockIdx.x*32, nb = blockIdx.y*32;
  const int tx = threadIdx.x & 31, ty = threadIdx.x >> 5;
#pragma unroll
  for (int i=0;i<32;i+=8) tile[ty+i][tx] = W[(size_t)(kb+ty+i)*N + (nb+tx)];
  __syncthreads();
#pragma unroll
  for (int i=0;i<32;i+=8) Wt[(size_t)(nb+ty+i)*K + (kb+tx)] = f2bf(tile[tx][ty+i]);
}

struct P7 { const float* s[7]; unsigned short* d[7]; };
__global__ __launch_bounds__(256)
void tconv7_k(P7 p)   // 7x (1024x1024) transposes batched on grid.z
{
  __shared__ float tile[32][33];
  const float* W = p.s[blockIdx.z];
  unsigned short* Wt = p.d[blockIdx.z];
  const int kb = blockIdx.x*32, nb = blockIdx.y*32;
  const int tx = threadIdx.x & 31, ty = threadIdx.x >> 5;
#pragma unroll
  for (int i=0;i<32;i+=8) tile[ty+i][tx] = W[(size_t)(kb+ty+i)*1024 + (nb+tx)];
  __syncthreads();
#pragma unroll
  for (int i=0;i<32;i+=8) Wt[(size_t)(nb+ty+i)*1024 + (kb+tx)] = f2bf(tile[tx][ty+i]);
}

__global__ __launch_bounds__(256)
void biascat_k(const float* bo, const float* ob, const float* bm, const float* bq,
               const float* bg, const float* bdu, const float* bp1, float* bc)
{
  const int i = blockIdx.x*256 + threadIdx.x;
  if (i >= 6144) return;
  const int s = i >> 10, d = i & 1023;
  float v;
  if (s==0) v = bo[d] + ob[d];
  else if (s==1) v = bm[d];
  else if (s==2) v = bq[d];
  else if (s==3) v = bg[d];
  else if (s==4) v = bdu[d];
  else v = bp1[d];
  bc[i] = v;
}

// ---------------- scans (half = 2 sequences, 128 chunk-rows of 64 steps) ----------------
__global__ __launch_bounds__(256)
void scan1_k(unsigned int* __restrict__ zgate, unsigned int* __restrict__ zmag,
             unsigned int* __restrict__ zomega, const unsigned int* __restrict__ zdt,
             const unsigned int* __restrict__ hb,
             float* __restrict__ sumPhi, float* __restrict__ sumGm)
{
  const int flat = blockIdx.x*256 + threadIdx.x;   // 128*(D/2) = 65536
  const int dh = flat & 511;
  const int bc = flat >> 9;                        // [0,128)
  size_t i = (size_t)bc*CHUNK*(D_/2) + dh;
  float sp0=0,sp1=0,sg0=0,sg1=0;
  for (int s=0;s<CHUNK;s++,i+=D_/2) {
    const unsigned ga=zgate[i], mg=zmag[i], om=zomega[i], dt=zdt[i], hh=hb[i];
    const float ga0=bflo(ga), ga1=bfhi(ga), mg0=bflo(mg), mg1=bfhi(mg);
    const float od0 = bflo(om)*bflo(dt)*0.01f, od1 = bfhi(om)*bfhi(dt)*0.01f;
    const unsigned odp = pack2(od0, od1);
    zomega[i] = odp;
    sp0 += bflo(odp); sp1 += bfhi(odp);
    const float g0 = ga0*mg0, g1 = ga1*mg1;
    const unsigned gmp = pack2(g0, g1);
    zmag[i] = gmp;
    sg0 += bflo(gmp); sg1 += bfhi(gmp);
    zgate[i] = pack2(g0*bflo(hh), g1*bfhi(hh));    // content
  }
  const int sidx = bc*D_ + dh*2;
  sumPhi[sidx]=sp0; sumPhi[sidx+1]=sp1;
  sumGm[sidx]=sg0;  sumGm[sidx+1]=sg1;
}

// wave-parallel exclusive scan over 64 chunks; one wave per (b,d) chain, 2 arrays
__global__ __launch_bounds__(256)
void scan2_k(float* __restrict__ a, float* __restrict__ b)
{
  const int chain = (blockIdx.x*256 + threadIdx.x) >> 6;  // [0, 2048): b*1024 + d
  const int lane  = threadIdx.x & 63;                     // chunk c
  const int bb = chain >> 10, d = chain & 1023;
  const size_t i = (size_t)(bb*64 + lane)*D_ + d;
  const float v = a[i], w = b[i];
  float vi = v, wi = w;
#pragma unroll
  for (int off=1; off<64; off<<=1) {
    const float t = __shfl_up(vi, off, 64);
    const float u = __shfl_up(wi, off, 64);
    if (lane >= off) { vi += t; wi += u; }
  }
  a[i] = vi - v;
  b[i] = wi - w;
}

__global__ __launch_bounds__(256)
void scan3_k(const unsigned int* __restrict__ omdt, const unsigned int* __restrict__ content,
             const unsigned int* __restrict__ phinit, const float* __restrict__ phiOff,
             float* __restrict__ sumRe, float* __restrict__ sumIm)
{
  const int flat = blockIdx.x*256 + threadIdx.x;
  const int dh = flat & 511;
  const int bc = flat >> 9;
  size_t i = (size_t)bc*CHUNK*(D_/2) + dh;
  const int sidx = bc*D_ + dh*2;
  float p0 = phiOff[sidx], p1 = phiOff[sidx+1];
  float re0=0,re1=0,im0=0,im1=0;
  for (int s=0;s<CHUNK;s++,i+=D_/2) {
    const unsigned od = omdt[i], ct = content[i], pi = phinit[i];
    p0 += bflo(od); p1 += bfhi(od);
    const float phi0 = bflo(pi)+p0, phi1 = bfhi(pi)+p1;
    float s0,c0,s1,c1;
    __sincosf(phi0,&s0,&c0);
    __sincosf(phi1,&s1,&c1);
    const float ct0=bflo(ct), ct1=bfhi(ct);
    re0 += ct0*c0; im0 += ct0*s0;
    re1 += ct1*c1; im1 += ct1*s1;
  }
  sumRe[sidx]=re0; sumRe[sidx+1]=re1;
  sumIm[sidx]=im0; sumIm[sidx+1]=im1;
}

__global__ __launch_bounds__(256)
void scan5_k(const unsigned int* __restrict__ omdt, const unsigned int* __restrict__ content,
             const unsigned int* __restrict__ phinit, const unsigned int* __restrict__ gm,
             const unsigned int* __restrict__ qoff,
             const float* __restrict__ phiOff, const float* __restrict__ gmOff,
             const float* __restrict__ reOff, const float* __restrict__ imOff,
             unsigned int* __restrict__ ctx)
{
  const int flat = blockIdx.x*256 + threadIdx.x;
  const int dh = flat & 511;
  const int bc = flat >> 9;
  size_t i = (size_t)bc*CHUNK*(D_/2) + dh;
  const int sidx = bc*D_ + dh*2;
  float p0 = phiOff[sidx], p1 = phiOff[sidx+1];
  float ag0 = gmOff[sidx], ag1 = gmOff[sidx+1];
  float re0 = reOff[sidx], re1 = reOff[sidx+1];
  float im0 = imOff[sidx], im1 = imOff[sidx+1];
  const int mtok0 = bc*CHUNK;
  for (int s=0;s<CHUNK;s++,i+=D_/2) {
    const unsigned od = omdt[i], ct = content[i], pi = phinit[i], gq = gm[i], qo = qoff[i];
    p0 += bflo(od); p1 += bfhi(od);
    const float phi0 = bflo(pi)+p0, phi1 = bfhi(pi)+p1;
    float sn0,cs0,sn1,cs1;
    __sincosf(phi0,&sn0,&cs0);
    __sincosf(phi1,&sn1,&cs1);
    const float ct0=bflo(ct), ct1=bfhi(ct);
    re0 += ct0*cs0; im0 += ct0*sn0;
    re1 += ct1*cs1; im1 += ct1*sn1;
    ag0 += bflo(gq); ag1 += bfhi(gq);
    const float inv0 = rsqrtf(ag0 + 1e-8f), inv1 = rsqrtf(ag1 + 1e-8f);
    const float mr0 = re0*inv0, mi0 = im0*inv0;
    const float mr1 = re1*inv1, mi1 = im1*inv1;
    const float pq0 = phi0 + bflo(qo), pq1 = phi1 + bfhi(qo);
    float sq0,cq0,sq1,cq1;
    __sincosf(pq0,&sq0,&cq0);
    __sincosf(pq1,&sq1,&cq1);
    const size_t cb = (size_t)(mtok0+s)*D_ + dh;   // u32 row = 1024
    ctx[cb]        = pack2(mr0*cq0 + mi0*sq0, mr1*cq1 + mi1*sq1);
    ctx[cb + D_/2] = pack2(mi0*cq0 - mr0*sq0, mi1*cq1 - mr1*sq1);
  }
}

// LayerNorm over 2048, in place on bf16 ctx; one block per token
__global__ __launch_bounds__(256)
void ln_k(unsigned int* __restrict__ ctx, const float* __restrict__ gam, const float* __restrict__ bet)
{
  const int m = blockIdx.x, tid = threadIdx.x;
  const size_t base = (size_t)m*1024 + tid*4;
  const uint4 t = *(const uint4*)(ctx + base);
  float v[8] = { bflo(t.x), bfhi(t.x), bflo(t.y), bfhi(t.y),
                 bflo(t.z), bfhi(t.z), bflo(t.w), bfhi(t.w) };
  float s=0.f, ss=0.f;
#pragma unroll
  for (int j=0;j<8;j++){ s+=v[j]; ss+=v[j]*v[j]; }
  for (int o=32;o;o>>=1){ s += __shfl_xor(s,o); ss += __shfl_xor(ss,o); }
  __shared__ float red[8];
  const int wv = tid>>6, lane = tid&63;
  if (lane==0){ red[wv]=s; red[4+wv]=ss; }
  __syncthreads();
  s  = red[0]+red[1]+red[2]+red[3];
  ss = red[4]+red[5]+red[6]+red[7];
  const float mu = s*(1.f/2048.f);
  const float rstd = rsqrtf(ss*(1.f/2048.f) - mu*mu + 1e-5f);
  const int col = tid*8;
  float o[8];
#pragma unroll
  for (int j=0;j<8;j++) o[j] = (v[j]-mu)*rstd*gam[col+j] + bet[col+j];
  uint4 w;
  w.x = pack2(o[0],o[1]); w.y = pack2(o[2],o[3]);
  w.z = pack2(o[4],o[5]); w.w = pack2(o[6],o[7]);
  *(uint4*)(ctx + base) = w;
}

extern "C" void kernel_launch(void* const* d_in, const int* in_sizes, int n_in,
                              void* d_out, int out_size, void* d_ws, size_t ws_size,
                              hipStream_t stream)
{
  const float* x     = (const float*)d_in[0];
  const float* Wdd   = (const float*)d_in[1];
  const float* Wdu   = (const float*)d_in[2];
  const float* bdu   = (const float*)d_in[3];
  const float* Wg    = (const float*)d_in[4];
  const float* bg    = (const float*)d_in[5];
  const float* Wp1   = (const float*)d_in[6];
  const float* bp1   = (const float*)d_in[7];
  const float* Wp2   = (const float*)d_in[8];
  const float* bp2   = (const float*)d_in[9];
  const float* obase = (const float*)d_in[10];
  const float* Wo    = (const float*)d_in[11];
  const float* bo    = (const float*)d_in[12];
  const float* Wm    = (const float*)d_in[13];
  const float* bm    = (const float*)d_in[14];
  const float* Wq    = (const float*)d_in[15];
  const float* bq    = (const float*)d_in[16];
  const float* lng   = (const float*)d_in[17];
  const float* lnb   = (const float*)d_in[18];
  const float* Wo1   = (const float*)d_in[19];
  const float* bo1   = (const float*)d_in[20];
  const float* Wo2   = (const float*)d_in[21];
  const float* bo2   = (const float*)d_in[22];

  char* basep = (char*)d_ws;
  size_t off = 0;
  auto alloc = [&](size_t n) { char* q = basep + off; off = (off + n + 255) & ~(size_t)255; return q; };

  const size_t S = (size_t)MH*1024;     // elements per [MH][1024] buffer
  // cat1 (6 slices) + hb contiguous: [omega][mag][qoff][gate][dt][phi1][hb]
  unsigned short* cat1 = (unsigned short*)alloc(7*S*2);                     // 117.4 MB
  unsigned short* zomega = cat1 + 0*S;
  unsigned short* zmag   = cat1 + 1*S;
  unsigned short* zqoff  = cat1 + 2*S;
  unsigned short* zgate  = cat1 + 3*S;
  unsigned short* zdt    = cat1 + 4*S;
  unsigned short* zphi1  = cat1 + 5*S;
  unsigned short* hb     = cat1 + 6*S;
  unsigned short* ctx    = zphi1;        // [MH][2048] aliases phi1+hb (both dead)
  unsigned short* a3     = cat1;         // [MH][1024] aliases omega (dead after scan5)
  unsigned short* zpin   = (unsigned short*)alloc(S*2);                     // 16.8 MB
  unsigned short* wt_cat = (unsigned short*)alloc((size_t)6144*1024*2);     // 12.6 MB
  unsigned short* wt_p2  = (unsigned short*)alloc(1024*1024*2);
  unsigned short* wt_du  = (unsigned short*)alloc(1024*128*2);
  unsigned short* wddb   = (unsigned short*)alloc(1024*128*2);
  unsigned short* wt_o1  = (unsigned short*)alloc((size_t)1024*2048*2);
  unsigned short* wt_o2  = (unsigned short*)alloc(1024*1024*2);
  float* bias_cat = (float*)alloc(6144*4);
  float* sumPhi = (float*)alloc((size_t)128*D_*4);
  float* sumGm  = (float*)alloc((size_t)128*D_*4);
  float* sumRe  = (float*)alloc((size_t)128*D_*4);
  float* sumIm  = (float*)alloc((size_t)128*D_*4);
  // total ~158 MB (same proven footprint)

  const dim3 blk(256);

  // ---- weight prep ----
  P7 p7;
  p7.s[0]=Wo;  p7.d[0]=wt_cat + (size_t)0*1024*1024;   // slice 0 omega
  p7.s[1]=Wm;  p7.d[1]=wt_cat + (size_t)1*1024*1024;   // slice 1 mag
  p7.s[2]=Wq;  p7.d[2]=wt_cat + (size_t)2*1024*1024;   // slice 2 qoff
  p7.s[3]=Wg;  p7.d[3]=wt_cat + (size_t)3*1024*1024;   // slice 3 gate
  p7.s[4]=Wp1; p7.d[4]=wt_cat + (size_t)5*1024*1024;   // slice 5 phi1
  p7.s[5]=Wp2; p7.d[5]=wt_p2;
  p7.s[6]=Wo2; p7.d[6]=wt_o2;
  tconv7_k<<<dim3(32,32,7), blk, 0, stream>>>(p7);
  tconv_k<<<dim3(4,32),  blk, 0, stream>>>(Wdu, wt_du, 128,1024);
  tconv_k<<<dim3(64,32), blk, 0, stream>>>(Wo1, wt_o1, 2048,1024);
  cvtx_k<<<128, blk, 0, stream>>>(Wdd, (unsigned int*)wddb);   // Wdd fp32 -> bf16, layout as-is
  // Wcomb^T[d][k] = (Wdd@Wdu)[k][d]: C = wt_du @ wddb^T (M=N=1024, K=128) -> slice 4
  gemmH<4,128><<<dim3(8,8), blk, 0, stream>>>(wt_du, wddb, nullptr, nullptr,
                                              wt_cat + (size_t)4*1024*1024, nullptr);
  biascat_k<<<24, blk, 0, stream>>>(bo, obase, bm, bq, bg, bdu, bp1, bias_cat);

  for (int h = 0; h < 2; h++) {
    const float* xh = x + (size_t)h*MH*D_;
    float* outh     = (float*)d_out + (size_t)h*MH*D_;

    cvtx_k<<<MH*D_/1024, blk, 0, stream>>>(xh, (unsigned int*)hb);

    // mega: all 6 projections (N=6144), grid 3072 blocks (~12/CU)
    gemmH<0,1024><<<dim3(MH/128, 48), blk, 0, stream>>>(hb, wt_cat, bias_cat,
                                                        nullptr, cat1, nullptr);
    // p2: phi_init (from gelu(phi1))
    gemmH<1,1024><<<dim3(MH/128, 8), blk, 0, stream>>>(zphi1, wt_p2, bp2,
                                                       nullptr, zpin, nullptr);
    // scans
    scan1_k<<<256, blk, 0, stream>>>((unsigned int*)zgate,(unsigned int*)zmag,(unsigned int*)zomega,
                                     (const unsigned int*)zdt,(const unsigned int*)hb, sumPhi, sumGm);
    scan2_k<<<512, blk, 0, stream>>>(sumPhi, sumGm);
    scan3_k<<<256, blk, 0, stream>>>((const unsigned int*)zomega,(const unsigned int*)zgate,
                                     (const unsigned int*)zpin, sumPhi, sumRe, sumIm);
    scan2_k<<<512, blk, 0, stream>>>(sumRe, sumIm);
    scan5_k<<<256, blk, 0, stream>>>((const unsigned int*)zomega,(const unsigned int*)zgate,
                                     (const unsigned int*)zpin,(const unsigned int*)zmag,
                                     (const unsigned int*)zqoff,
                                     sumPhi, sumGm, sumRe, sumIm, (unsigned int*)ctx);

    // tail: LN + out MLP + residual
    ln_k<<<MH, blk, 0, stream>>>((unsigned int*)ctx, lng, lnb);
    gemmH<2,2048><<<dim3(MH/128, 8), blk, 0, stream>>>(ctx, wt_o1, bo1,
                                                       nullptr, a3, nullptr);
    gemmH<3,1024><<<dim3(MH/128, 8), blk, 0, stream>>>(a3, wt_o2, bo2,
                                                       xh, nullptr, outh);
  }
}